// Round 6
// baseline (6643.155 us; speedup 1.0000x reference)
//
#include <hip/hip_runtime.h>
#include <math.h>

#define SEQ 2048
#define DIM 2048
#define NH 16
#define HD 128
#define CACHEB 408
#define RECENT 204
#define PEN 0.4f
#define QK_SCALE 0.08838834764831845f  // 1/sqrt(128)
#define BIGT 0x7fffffff

// ---------------- generic f32 GEMM: C = scale * A(MxK) * B(NxK)^T ----------
__global__ __launch_bounds__(256)
void gemm_nt(const float* __restrict__ A, const float* __restrict__ B,
             float* __restrict__ C, int M, int N, int K,
             int lda, int ldb, int ldc,
             long aBatch, long bBatch, long cBatch,
             float scale, int causal, int trunc_a)
{
    A += (long)blockIdx.z * aBatch;
    B += (long)blockIdx.z * bBatch;
    C += (long)blockIdx.z * cBatch;
    int m0 = blockIdx.y * 64, n0 = blockIdx.x * 64;
    if (causal && n0 > m0 + 63) return;           // tile entirely above diagonal
    int Keff = trunc_a ? min(K, m0 + 64) : K;     // A rows are zero past diag (probs)

    __shared__ float As[16][64];
    __shared__ float Bs[16][64];
    int tid = threadIdx.x;
    int tx = tid & 15, ty = tid >> 4;
    int lrow = tid >> 2;           // 0..63
    int lcol = (tid & 3) << 2;     // 0,4,8,12
    float acc[4][4] = {};

    for (int k0 = 0; k0 < Keff; k0 += 16) {
        float4 a4 = *(const float4*)(A + (size_t)(m0 + lrow) * lda + k0 + lcol);
        float4 b4 = *(const float4*)(B + (size_t)(n0 + lrow) * ldb + k0 + lcol);
        __syncthreads();
        As[lcol+0][lrow]=a4.x; As[lcol+1][lrow]=a4.y; As[lcol+2][lrow]=a4.z; As[lcol+3][lrow]=a4.w;
        Bs[lcol+0][lrow]=b4.x; Bs[lcol+1][lrow]=b4.y; Bs[lcol+2][lrow]=b4.z; Bs[lcol+3][lrow]=b4.w;
        __syncthreads();
        #pragma unroll
        for (int kk = 0; kk < 16; kk++) {
            float4 av = *(const float4*)&As[kk][ty*4];
            float4 bv = *(const float4*)&Bs[kk][tx*4];
            float a_[4] = {av.x, av.y, av.z, av.w};
            float b_[4] = {bv.x, bv.y, bv.z, bv.w};
            #pragma unroll
            for (int i = 0; i < 4; i++)
                #pragma unroll
                for (int j = 0; j < 4; j++)
                    acc[i][j] = fmaf(a_[i], b_[j], acc[i][j]);
        }
    }
    #pragma unroll
    for (int i = 0; i < 4; i++) {
        float4 o;
        o.x = acc[i][0]*scale; o.y = acc[i][1]*scale;
        o.z = acc[i][2]*scale; o.w = acc[i][3]*scale;
        *(float4*)(C + (size_t)(m0 + ty*4 + i) * ldc + n0 + tx*4) = o;
    }
}

// ---------------- RoPE in place on Q and K --------------------------------
__global__ __launch_bounds__(256)
void rope_qk(float* __restrict__ Q, float* __restrict__ K, const int* __restrict__ pos_ids)
{
    int s = blockIdx.x;
    int i = threadIdx.x & 63;
    int h = blockIdx.y * 4 + (threadIdx.x >> 6);
    double p = (double)pos_ids[s];
    double invf = exp(-((double)(2 * i) / (double)HD) * 9.210340371976184); // ln(10000)
    double ang = p * invf;
    float c = (float)cos(ang), sn = (float)sin(ang);
    size_t b = (size_t)s * DIM + (size_t)h * HD;
    float q0 = Q[b + i], q1 = Q[b + i + 64];
    Q[b + i]      = q0 * c - q1 * sn;
    Q[b + i + 64] = q1 * c + q0 * sn;
    float k0 = K[b + i], k1 = K[b + i + 64];
    K[b + i]      = k0 * c - k1 * sn;
    K[b + i + 64] = k1 * c + k0 * sn;
}

// ---------------- V -> Vt[h][hd][s] ---------------------------------------
__global__ __launch_bounds__(1024)
void transpose_v(const float* __restrict__ V, float* __restrict__ Vt)
{
    __shared__ float tile[32][33];
    int h = blockIdx.z;
    int j0 = blockIdx.x * 32, d0 = blockIdx.y * 32;
    int tx = threadIdx.x, ty = threadIdx.y;
    tile[ty][tx] = V[(size_t)(j0 + ty) * DIM + (size_t)h * HD + d0 + tx];
    __syncthreads();
    Vt[(size_t)h * HD * SEQ + (size_t)(d0 + ty) * SEQ + j0 + tx] = tile[tx][ty];
}

// ---------------- row softmax (causal) in place on Sc ---------------------
__global__ __launch_bounds__(256)
void softmax_rows(float* __restrict__ Sc)
{
    int r = blockIdx.x, h = blockIdx.y;
    float* row = Sc + ((size_t)h * SEQ + r) * SEQ;
    int n = r + 1;
    __shared__ float red[256];
    int tid = threadIdx.x;
    float mx = -INFINITY;
    for (int j = tid; j < n; j += 256) mx = fmaxf(mx, row[j]);
    red[tid] = mx; __syncthreads();
    for (int s = 128; s; s >>= 1) { if (tid < s) red[tid] = fmaxf(red[tid], red[tid + s]); __syncthreads(); }
    mx = red[0]; __syncthreads();
    float sum = 0.f;
    for (int j = tid; j < n; j += 256) { float e = expf(row[j] - mx); row[j] = e; sum += e; }
    red[tid] = sum; __syncthreads();
    for (int s = 128; s; s >>= 1) { if (tid < s) red[tid] += red[tid + s]; __syncthreads(); }
    float inv = 1.f / red[0];
    for (int j = tid; j < n; j += 256) row[j] *= inv;
    for (int j = n + tid; j < SEQ; j += 256) row[j] = 0.f;
}

// ---------------- parallel warmup: select0[h][c] = sum_t PEN^(407-t)*Sc[t][c]
__global__ __launch_bounds__(256)
void warmup_select(const float* __restrict__ Sc, float* __restrict__ sel0)
{
    int h = blockIdx.y;
    int col = blockIdx.x * 256 + threadIdx.x;
    const float* S = Sc + (size_t)h * SEQ * SEQ + col;
    float s = 0.f;
    #pragma unroll 4
    for (int t = 0; t < CACHEB; t++) s = PEN * s + S[(size_t)t * SEQ];
    sel0[h * SEQ + col] = s;
}

// ---------------- DPP cross-lane helpers (VALU-speed, no LDS) -------------
#define DPP_SUMSTEP(x, ctrl) \
    x += __int_as_float(__builtin_amdgcn_update_dpp(0, __float_as_int(x), ctrl, 0xF, 0xF, true))
#define DPP_SUMBC(x, ctrl) \
    x += __int_as_float(__builtin_amdgcn_update_dpp(0, __float_as_int(x), ctrl, 0xF, 0xF, false))
#define DPP_MINF(x, ctrl) \
    x = fminf(x, __int_as_float(__builtin_amdgcn_update_dpp(__float_as_int(x), __float_as_int(x), ctrl, 0xF, 0xF, false)))
#define DPP_MINU(x, ctrl) \
    { unsigned t_ = (unsigned)__builtin_amdgcn_update_dpp((int)(x), (int)(x), ctrl, 0xF, 0xF, false); x = t_ < x ? t_ : x; }

__device__ __forceinline__ float wave_sum64(float x) {
    DPP_SUMSTEP(x, 0x111); DPP_SUMSTEP(x, 0x112);
    DPP_SUMSTEP(x, 0x114); DPP_SUMSTEP(x, 0x118);
    DPP_SUMBC(x, 0x142);   DPP_SUMBC(x, 0x143);
    return __int_as_float(__builtin_amdgcn_readlane(__float_as_int(x), 63));
}
__device__ __forceinline__ float wave_min64f(float x) {
    DPP_MINF(x, 0x111); DPP_MINF(x, 0x112);
    DPP_MINF(x, 0x114); DPP_MINF(x, 0x118);
    DPP_MINF(x, 0x142); DPP_MINF(x, 0x143);
    return __int_as_float(__builtin_amdgcn_readlane(__float_as_int(x), 63));
}
__device__ __forceinline__ unsigned wave_min64u(unsigned x) {
    DPP_MINU(x, 0x111); DPP_MINU(x, 0x112);
    DPP_MINU(x, 0x114); DPP_MINU(x, 0x118);
    DPP_MINU(x, 0x142); DPP_MINU(x, 0x143);
    return (unsigned)__builtin_amdgcn_readlane((int)x, 63);
}

// async global->LDS copy, 16B/lane, dest = lds_base + lane*16 (wave-uniform base)
__device__ __forceinline__ void gload_lds16(const float* g, float* l) {
    __builtin_amdgcn_global_load_lds(
        (const __attribute__((address_space(1))) unsigned int*)g,
        (__attribute__((address_space(3))) unsigned int*)l, 16, 0, 0);
}
// wait until <= n vector-memory ops outstanding (lgkm/exp: don't wait)
#define WAIT_VMCNT(n) __builtin_amdgcn_s_waitcnt(((n)&15)|(((n)>>4)<<14)|0xF70)

#define SLOTS 6
#define DEPTH 4

// ---------------- H2O greedy eviction scan (v5: LDS-ring async staging) ---
// One wave per head. Lane l owns cols {i*256 + l*4 + j : i in [0,8), j in [0,4)}.
// Rows stream HBM -> LDS ring via global_load_lds (no dest regs, no forced
// vmcnt drain); LDS -> regs double-buffered one step ahead.
__global__ __launch_bounds__(64, 1)
void h2o_scan3(const float* __restrict__ Sc, const float* __restrict__ sel0,
               int* __restrict__ evict)
{
    __shared__ float ring[SLOTS * SEQ];   // 48 KB
    __shared__ int et[SEQ];               // 8 KB
    int h = blockIdx.x;
    int l = threadIdx.x;
    const float* Sh = Sc + (size_t)h * SEQ * SEQ;
    const float* gbase = Sh + (l << 2);

    #pragma unroll
    for (int s = 0; s < SEQ / 64; s++) et[s * 64 + l] = BIGT;

    float sel[32];
    const float* s0 = sel0 + h * SEQ + l * 4;
    #pragma unroll
    for (int i = 0; i < 8; i++) {
        float4 v = *(const float4*)(s0 + i * 256);
        sel[i*4+0]=v.x; sel[i*4+1]=v.y; sel[i*4+2]=v.z; sel[i*4+3]=v.w;
    }

    // preload rows CACHEB..CACHEB+3 into ring slots (CACHEB%6==0 -> slots 0..3)
    #pragma unroll
    for (int j = 0; j < DEPTH; j++) {
        const float* g = gbase + (size_t)(CACHEB + j) * SEQ;
        float* lp = &ring[((CACHEB + j) % SLOTS) * SEQ];
        #pragma unroll
        for (int i = 0; i < 8; i++) gload_lds16(g + i * 256, lp + i * 256);
    }
    WAIT_VMCNT(16);                       // rows CACHEB, CACHEB+1 resident

    float4 cur[8], nxt[8];
    {
        const float* lp = &ring[(CACHEB % SLOTS) * SEQ];
        #pragma unroll
        for (int i = 0; i < 8; i++) cur[i] = *(const float4*)(lp + i * 256 + l * 4);
    }

    unsigned mask = 0xffffffffu;          // bit k=i*4+j: col i*256+l*4+j alive
    unsigned candBits = 0;                // bit k: col <= t-RECENT (incremental)
    #pragma unroll
    for (int k = 0; k < 32; k++) {
        int p = ((k >> 2) << 8) + l * 4 + (k & 3);
        if (p <= CACHEB - RECENT) candBits |= 1u << k;
    }

    for (int t = CACHEB; t < SEQ - 1; t++) {
        // ---- issue async prefetch of row t+DEPTH (clamped; same-slot rewrite) ----
        int pr = t + DEPTH; if (pr > SEQ - 1) pr = SEQ - 1;
        {
            const float* g = gbase + (size_t)pr * SEQ;
            float* lp = &ring[(pr % SLOTS) * SEQ];
            #pragma unroll
            for (int i = 0; i < 8; i++) gload_lds16(g + i * 256, lp + i * 256);
        }
        // outstanding <= 32 (rows t+1..t+DEPTH); retire oldest 8 -> row t+1 done
        WAIT_VMCNT(24);
        // ---- LDS -> regs for row t+1 (consumed next iteration) ----
        {
            const float* lp = &ring[((t + 1) % SLOTS) * SEQ];
            #pragma unroll
            for (int i = 0; i < 8; i++) nxt[i] = *(const float4*)(lp + i * 256 + l * 4);
        }

        // ---- masked values m[k] (once), partial sums (4 chains) ----
        float m[32];
        float p0 = 0.f, p1 = 0.f, p2 = 0.f, p3 = 0.f;
        #pragma unroll
        for (int i = 0; i < 8; i++) {
            float4 b = cur[i];
            m[i*4+0] = (mask & (1u << (i*4+0))) ? b.x : 0.f;
            m[i*4+1] = (mask & (1u << (i*4+1))) ? b.y : 0.f;
            m[i*4+2] = (mask & (1u << (i*4+2))) ? b.z : 0.f;
            m[i*4+3] = (mask & (1u << (i*4+3))) ? b.w : 0.f;
            p0 += m[i*4+0]; p1 += m[i*4+1]; p2 += m[i*4+2]; p3 += m[i*4+3];
        }
        // pre-scale sel while the DPP sum is in flight
        #pragma unroll
        for (int k = 0; k < 32; k++) sel[k] *= PEN;
        float part = wave_sum64((p0 + p1) + (p2 + p3));
        float inv = 1.f / part;

        // ---- sel update + candidate-masked value ----
        unsigned cm = mask & candBits;
        float cv[32];
        #pragma unroll
        for (int k = 0; k < 32; k++) {
            float s2 = fmaf(m[k], inv, sel[k]);
            sel[k] = s2;
            cv[k] = ((cm >> k) & 1u) ? s2 : INFINITY;
        }
        // ---- local min tree, then DPP min across lanes ----
        float m16[16];
        #pragma unroll
        for (int k = 0; k < 16; k++) m16[k] = fminf(cv[k], cv[k + 16]);
        float m8[8];
        #pragma unroll
        for (int k = 0; k < 8; k++) m8[k] = fminf(m16[k], m16[k + 8]);
        float m4[4];
        #pragma unroll
        for (int k = 0; k < 4; k++) m4[k] = fminf(m8[k], m8[k + 4]);
        float lmin = fminf(fminf(m4[0], m4[1]), fminf(m4[2], m4[3]));
        float gm = wave_min64f(lmin);

        // ---- first matching column: bitmask + ffs, then DPP min pos ----
        unsigned mb = 0;
        #pragma unroll
        for (int k = 0; k < 32; k++) mb |= (cv[k] == gm) ? (1u << k) : 0u;
        int mk = __ffs(mb) - 1;
        unsigned lpos = mb ? (unsigned)(((mk >> 2) << 8) + l * 4 + (mk & 3))
                           : 0xffffffffu;
        unsigned bpos = wave_min64u(lpos);

        // ---- evict ----
        int ke = (((bpos >> 8) << 2) | (bpos & 3));
        if ((((int)bpos >> 2) & 63) == l) mask &= ~(1u << ke);
        if (l == 0) et[bpos] = t;

        // ---- candidate set grows by one col for step t+1 ----
        int newc = t + 1 - RECENT;
        if (((newc >> 2) & 63) == l) candBits |= 1u << (((newc >> 8) << 2) | (newc & 3));

        // ---- rotate register double-buffer ----
        #pragma unroll
        for (int i = 0; i < 8; i++) cur[i] = nxt[i];
    }

    #pragma unroll
    for (int s = 0; s < SEQ / 64; s++)
        evict[h * SEQ + s * 64 + l] = et[s * 64 + l];
}

// ---------------- apply mask + renormalize rows >= CACHEB in place --------
__global__ __launch_bounds__(256)
void mask_renorm(float* __restrict__ Sc, const int* __restrict__ evict)
{
    int r = CACHEB + blockIdx.x;
    int h = blockIdx.y;
    float* row = Sc + ((size_t)h * SEQ + r) * SEQ;
    const int* et = evict + h * SEQ;
    int tid = threadIdx.x;
    __shared__ float red[256];
    float v[8]; float sum = 0.f;
    #pragma unroll
    for (int s = 0; s < 8; s++) {
        int c = s * 256 + tid;
        float x = row[c];
        v[s] = (et[c] >= r) ? x : 0.f;
        sum += v[s];
    }
    red[tid] = sum; __syncthreads();
    for (int s = 128; s; s >>= 1) { if (tid < s) red[tid] += red[tid + s]; __syncthreads(); }
    float inv = 1.f / red[0];
    #pragma unroll
    for (int s = 0; s < 8; s++) row[s * 256 + tid] = v[s] * inv;
}

extern "C" void kernel_launch(void* const* d_in, const int* in_sizes, int n_in,
                              void* d_out, int out_size, void* d_ws, size_t ws_size,
                              hipStream_t stream)
{
    const float* hidden = (const float*)d_in[0];
    const int*   pos    = (const int*)d_in[2];
    const float* wq     = (const float*)d_in[3];
    const float* wk     = (const float*)d_in[4];
    const float* wv     = (const float*)d_in[5];
    const float* wo     = (const float*)d_in[6];
    float* out = (float*)d_out;

    float* ws = (float*)d_ws;
    const size_t SD = (size_t)SEQ * DIM;
    float* Q    = ws;            // 16 MB
    float* K    = ws + SD;       // 16 MB
    float* V    = ws + 2 * SD;   // 16 MB; reused as O after transpose_v
    float* Vt   = ws + 3 * SD;   // 16 MB
    float* O    = V;             // alias: V dead once Vt exists
    float* sel0 = ws + 4 * SD;                 // NH*SEQ floats
    int*   evct = (int*)(ws + 4 * SD + (size_t)NH * SEQ);  // NH*SEQ ints
    float* Sc   = ws + 4 * SD + 2 * (size_t)NH * SEQ;      // g * SEQ*SEQ floats

    const size_t fixedB   = (4 * SD + 2 * (size_t)NH * SEQ) * sizeof(float);
    const size_t perHeadB = (size_t)SEQ * SEQ * sizeof(float);
    int g = NH;
    while (g > 1 && fixedB + (size_t)g * perHeadB > ws_size) g >>= 1;

    // 1. projections: X @ W^T
    gemm_nt<<<dim3(32, 32, 1), 256, 0, stream>>>(hidden, wq, Q, SEQ, DIM, DIM,
        DIM, DIM, DIM, 0, 0, 0, 1.f, 0, 0);
    gemm_nt<<<dim3(32, 32, 1), 256, 0, stream>>>(hidden, wk, K, SEQ, DIM, DIM,
        DIM, DIM, DIM, 0, 0, 0, 1.f, 0, 0);
    gemm_nt<<<dim3(32, 32, 1), 256, 0, stream>>>(hidden, wv, V, SEQ, DIM, DIM,
        DIM, DIM, DIM, 0, 0, 0, 1.f, 0, 0);

    // 2. RoPE on Q, K
    rope_qk<<<dim3(SEQ, NH / 4), 256, 0, stream>>>(Q, K, pos);

    // 3. V -> Vt[h][hd][s]  (after this, V's storage becomes O)
    transpose_v<<<dim3(SEQ / 32, HD / 32, NH), dim3(32, 32), 0, stream>>>(V, Vt);

    // 4-8 per head-group (score buffer reused across groups)
    for (int h0 = 0; h0 < NH; h0 += g) {
        int gc = min(g, NH - h0);
        gemm_nt<<<dim3(32, 32, gc), 256, 0, stream>>>(
            Q + (size_t)h0 * HD, K + (size_t)h0 * HD, Sc, SEQ, SEQ, HD,
            DIM, DIM, SEQ, HD, HD, (long)SEQ * SEQ, QK_SCALE, 1, 0);
        softmax_rows<<<dim3(SEQ, gc), 256, 0, stream>>>(Sc);
        warmup_select<<<dim3(SEQ / 256, gc), 256, 0, stream>>>(Sc, sel0);
        h2o_scan3<<<dim3(gc), 64, 0, stream>>>(Sc, sel0, evct);
        mask_renorm<<<dim3(SEQ - CACHEB, gc), 256, 0, stream>>>(Sc, evct);
        gemm_nt<<<dim3(HD / 64, 32, gc), 256, 0, stream>>>(
            Sc, Vt + (size_t)h0 * HD * SEQ, O + (size_t)h0 * HD, SEQ, HD, SEQ,
            SEQ, SEQ, DIM, (long)SEQ * SEQ, (long)HD * SEQ, HD, 1.f, 0, 1);
    }

    // 9. final projection: out = O @ wo^T
    gemm_nt<<<dim3(32, 32, 1), 256, 0, stream>>>(O, wo, out, SEQ, DIM, DIM,
        DIM, DIM, DIM, 0, 0, 0, 1.f, 0, 0);
}

// Round 7
// 5868.506 us; speedup vs baseline: 1.1320x; 1.1320x over previous
//
#include <hip/hip_runtime.h>
#include <math.h>

#define SEQ 2048
#define DIM 2048
#define NH 16
#define HD 128
#define CACHEB 408
#define RECENT 204
#define PEN 0.4f
#define QK_SCALE 0.08838834764831845f  // 1/sqrt(128)
#define BIGT 0x7fffffff

// ---------------- generic f32 GEMM: C = scale * A(MxK) * B(NxK)^T ----------
__global__ __launch_bounds__(256)
void gemm_nt(const float* __restrict__ A, const float* __restrict__ B,
             float* __restrict__ C, int M, int N, int K,
             int lda, int ldb, int ldc,
             long aBatch, long bBatch, long cBatch,
             float scale, int causal, int trunc_a)
{
    A += (long)blockIdx.z * aBatch;
    B += (long)blockIdx.z * bBatch;
    C += (long)blockIdx.z * cBatch;
    int m0 = blockIdx.y * 64, n0 = blockIdx.x * 64;
    if (causal && n0 > m0 + 63) return;           // tile entirely above diagonal
    int Keff = trunc_a ? min(K, m0 + 64) : K;     // A rows are zero past diag (probs)

    __shared__ float As[16][64];
    __shared__ float Bs[16][64];
    int tid = threadIdx.x;
    int tx = tid & 15, ty = tid >> 4;
    int lrow = tid >> 2;           // 0..63
    int lcol = (tid & 3) << 2;     // 0,4,8,12
    float acc[4][4] = {};

    for (int k0 = 0; k0 < Keff; k0 += 16) {
        float4 a4 = *(const float4*)(A + (size_t)(m0 + lrow) * lda + k0 + lcol);
        float4 b4 = *(const float4*)(B + (size_t)(n0 + lrow) * ldb + k0 + lcol);
        __syncthreads();
        As[lcol+0][lrow]=a4.x; As[lcol+1][lrow]=a4.y; As[lcol+2][lrow]=a4.z; As[lcol+3][lrow]=a4.w;
        Bs[lcol+0][lrow]=b4.x; Bs[lcol+1][lrow]=b4.y; Bs[lcol+2][lrow]=b4.z; Bs[lcol+3][lrow]=b4.w;
        __syncthreads();
        #pragma unroll
        for (int kk = 0; kk < 16; kk++) {
            float4 av = *(const float4*)&As[kk][ty*4];
            float4 bv = *(const float4*)&Bs[kk][tx*4];
            float a_[4] = {av.x, av.y, av.z, av.w};
            float b_[4] = {bv.x, bv.y, bv.z, bv.w};
            #pragma unroll
            for (int i = 0; i < 4; i++)
                #pragma unroll
                for (int j = 0; j < 4; j++)
                    acc[i][j] = fmaf(a_[i], b_[j], acc[i][j]);
        }
    }
    #pragma unroll
    for (int i = 0; i < 4; i++) {
        float4 o;
        o.x = acc[i][0]*scale; o.y = acc[i][1]*scale;
        o.z = acc[i][2]*scale; o.w = acc[i][3]*scale;
        *(float4*)(C + (size_t)(m0 + ty*4 + i) * ldc + n0 + tx*4) = o;
    }
}

// ---------------- RoPE in place on Q and K --------------------------------
__global__ __launch_bounds__(256)
void rope_qk(float* __restrict__ Q, float* __restrict__ K, const int* __restrict__ pos_ids)
{
    int s = blockIdx.x;
    int i = threadIdx.x & 63;
    int h = blockIdx.y * 4 + (threadIdx.x >> 6);
    double p = (double)pos_ids[s];
    double invf = exp(-((double)(2 * i) / (double)HD) * 9.210340371976184); // ln(10000)
    double ang = p * invf;
    float c = (float)cos(ang), sn = (float)sin(ang);
    size_t b = (size_t)s * DIM + (size_t)h * HD;
    float q0 = Q[b + i], q1 = Q[b + i + 64];
    Q[b + i]      = q0 * c - q1 * sn;
    Q[b + i + 64] = q1 * c + q0 * sn;
    float k0 = K[b + i], k1 = K[b + i + 64];
    K[b + i]      = k0 * c - k1 * sn;
    K[b + i + 64] = k1 * c + k0 * sn;
}

// ---------------- V -> Vt[h][hd][s] ---------------------------------------
__global__ __launch_bounds__(1024)
void transpose_v(const float* __restrict__ V, float* __restrict__ Vt)
{
    __shared__ float tile[32][33];
    int h = blockIdx.z;
    int j0 = blockIdx.x * 32, d0 = blockIdx.y * 32;
    int tx = threadIdx.x, ty = threadIdx.y;
    tile[ty][tx] = V[(size_t)(j0 + ty) * DIM + (size_t)h * HD + d0 + tx];
    __syncthreads();
    Vt[(size_t)h * HD * SEQ + (size_t)(d0 + ty) * SEQ + j0 + tx] = tile[tx][ty];
}

// ---------------- row softmax (causal) in place on Sc ---------------------
__global__ __launch_bounds__(256)
void softmax_rows(float* __restrict__ Sc)
{
    int r = blockIdx.x, h = blockIdx.y;
    float* row = Sc + ((size_t)h * SEQ + r) * SEQ;
    int n = r + 1;
    __shared__ float red[256];
    int tid = threadIdx.x;
    float mx = -INFINITY;
    for (int j = tid; j < n; j += 256) mx = fmaxf(mx, row[j]);
    red[tid] = mx; __syncthreads();
    for (int s = 128; s; s >>= 1) { if (tid < s) red[tid] = fmaxf(red[tid], red[tid + s]); __syncthreads(); }
    mx = red[0]; __syncthreads();
    float sum = 0.f;
    for (int j = tid; j < n; j += 256) { float e = expf(row[j] - mx); row[j] = e; sum += e; }
    red[tid] = sum; __syncthreads();
    for (int s = 128; s; s >>= 1) { if (tid < s) red[tid] += red[tid + s]; __syncthreads(); }
    float inv = 1.f / red[0];
    for (int j = tid; j < n; j += 256) row[j] *= inv;
    for (int j = n + tid; j < SEQ; j += 256) row[j] = 0.f;
}

// ---------------- parallel warmup: select0[h][c] = sum_t PEN^(407-t)*Sc[t][c]
__global__ __launch_bounds__(256)
void warmup_select(const float* __restrict__ Sc, float* __restrict__ sel0)
{
    int h = blockIdx.y;
    int col = blockIdx.x * 256 + threadIdx.x;
    const float* S = Sc + (size_t)h * SEQ * SEQ + col;
    float s = 0.f;
    #pragma unroll 4
    for (int t = 0; t < CACHEB; t++) s = PEN * s + S[(size_t)t * SEQ];
    sel0[h * SEQ + col] = s;
}

// ---------------- DPP cross-lane helpers (VALU-speed, no LDS) -------------
#define DPP_SUMSTEP(x, ctrl) \
    x += __int_as_float(__builtin_amdgcn_update_dpp(0, __float_as_int(x), ctrl, 0xF, 0xF, true))
#define DPP_SUMBC(x, ctrl) \
    x += __int_as_float(__builtin_amdgcn_update_dpp(0, __float_as_int(x), ctrl, 0xF, 0xF, false))
#define DPP_MINF(x, ctrl) \
    x = fminf(x, __int_as_float(__builtin_amdgcn_update_dpp(__float_as_int(x), __float_as_int(x), ctrl, 0xF, 0xF, false)))
#define DPP_MINU(x, ctrl) \
    { unsigned t_ = (unsigned)__builtin_amdgcn_update_dpp((int)(x), (int)(x), ctrl, 0xF, 0xF, false); x = t_ < x ? t_ : x; }

__device__ __forceinline__ float wave_sum64(float x) {
    DPP_SUMSTEP(x, 0x111); DPP_SUMSTEP(x, 0x112);
    DPP_SUMSTEP(x, 0x114); DPP_SUMSTEP(x, 0x118);
    DPP_SUMBC(x, 0x142);   DPP_SUMBC(x, 0x143);
    return __int_as_float(__builtin_amdgcn_readlane(__float_as_int(x), 63));
}
__device__ __forceinline__ float wave_min64f(float x) {
    DPP_MINF(x, 0x111); DPP_MINF(x, 0x112);
    DPP_MINF(x, 0x114); DPP_MINF(x, 0x118);
    DPP_MINF(x, 0x142); DPP_MINF(x, 0x143);
    return __int_as_float(__builtin_amdgcn_readlane(__float_as_int(x), 63));
}
__device__ __forceinline__ unsigned wave_min64u(unsigned x) {
    DPP_MINU(x, 0x111); DPP_MINU(x, 0x112);
    DPP_MINU(x, 0x114); DPP_MINU(x, 0x118);
    DPP_MINU(x, 0x142); DPP_MINU(x, 0x143);
    return (unsigned)__builtin_amdgcn_readlane((int)x, 63);
}

#define SLOTS 8

// ---------------- H2O scan (v6: producer/consumer wave specialization) ----
// 128 threads/head. Wave 1 streams rows HBM->LDS ring (all vmcnt waits live
// here, OFF the serial chain). Wave 0 (consumer) does the serial recurrence
// touching LDS only -> its chain has no vmcnt at all.
__global__ __launch_bounds__(128, 1)
void h2o_scan4(const float* __restrict__ Sc, const float* __restrict__ sel0,
               int* __restrict__ evict)
{
    __shared__ float ring[SLOTS * SEQ];   // 64 KB
    __shared__ int et[SEQ];               // 8 KB
    __shared__ int prodF, consF;

    int h = blockIdx.x;
    int tid = threadIdx.x;
    int l = tid & 63;
    int wv = tid >> 6;
    const float* Sh = Sc + (size_t)h * SEQ * SEQ;
    const float* gb = Sh + (l << 2);

    if (tid == 0) { prodF = CACHEB; consF = CACHEB - 1; }
    __syncthreads();

    if (wv == 1) {
        // ================= producer =================
        float4 ba[8], bb[8], bc[8];
        auto loadrow = [&](int r, float4 (&b)[8]) {
            const float* g = gb + (size_t)r * SEQ;
            #pragma unroll
            for (int i = 0; i < 8; i++) b[i] = *(const float4*)(g + i * 256);
        };
        auto writerow = [&](int r, float4 (&b)[8]) {
            while (*(volatile int*)&consF < r - SLOTS) __builtin_amdgcn_s_sleep(2);
            float* lp = &ring[(r % SLOTS) * SEQ] + (l << 2);
            #pragma unroll
            for (int i = 0; i < 8; i++) *(float4*)(lp + i * 256) = b[i];
            __threadfence_block();                 // data before flag
            if (l == 0) *(volatile int*)&prodF = r + 1;
        };
        loadrow(CACHEB, ba); loadrow(CACHEB + 1, bb); loadrow(CACHEB + 2, bc);
        for (int r = CACHEB; r < SEQ; r += 3) {
            writerow(r, ba); if (r + 3 < SEQ) loadrow(r + 3, ba);
            if (r + 1 < SEQ) { writerow(r + 1, bb); if (r + 4 < SEQ) loadrow(r + 4, bb); }
            if (r + 2 < SEQ) { writerow(r + 2, bc); if (r + 5 < SEQ) loadrow(r + 5, bc); }
        }
        return;
    }

    // ================= consumer (serial chain: LDS only) =================
    #pragma unroll
    for (int s = 0; s < SEQ / 64; s++) et[s * 64 + l] = BIGT;

    float sel[32];
    const float* s0 = sel0 + h * SEQ + l * 4;
    #pragma unroll
    for (int i = 0; i < 8; i++) {
        float4 v = *(const float4*)(s0 + i * 256);
        sel[i*4+0]=v.x; sel[i*4+1]=v.y; sel[i*4+2]=v.z; sel[i*4+3]=v.w;
    }

    while (*(volatile int*)&prodF < CACHEB + 1) __builtin_amdgcn_s_sleep(1);
    float4 cur[8], nxt[8];
    {
        const float* lp = &ring[(CACHEB % SLOTS) * SEQ] + (l << 2);
        #pragma unroll
        for (int i = 0; i < 8; i++) cur[i] = *(const float4*)(lp + i * 256);
    }

    unsigned mask = 0xffffffffu;          // bit k=i*4+j: col i*256+l*4+j alive
    unsigned candBits = 0;                // bit k: col <= t-RECENT (incremental)
    #pragma unroll
    for (int k = 0; k < 32; k++) {
        int p = ((k >> 2) << 8) + l * 4 + (k & 3);
        if (p <= CACHEB - RECENT) candBits |= 1u << k;
    }

    for (int t = CACHEB; t < SEQ - 1; t++) {
        // row t+1 ready? (producer ~SLOTS ahead -> usually one poll)
        while (*(volatile int*)&prodF < t + 2) __builtin_amdgcn_s_sleep(1);
        {
            const float* lp = &ring[((t + 1) % SLOTS) * SEQ] + (l << 2);
            #pragma unroll
            for (int i = 0; i < 8; i++) nxt[i] = *(const float4*)(lp + i * 256);
        }

        // ---- masked values m[k] (once), partial sums (4 chains) ----
        float m[32];
        float p0 = 0.f, p1 = 0.f, p2 = 0.f, p3 = 0.f;
        #pragma unroll
        for (int i = 0; i < 8; i++) {
            float4 b = cur[i];
            m[i*4+0] = (mask & (1u << (i*4+0))) ? b.x : 0.f;
            m[i*4+1] = (mask & (1u << (i*4+1))) ? b.y : 0.f;
            m[i*4+2] = (mask & (1u << (i*4+2))) ? b.z : 0.f;
            m[i*4+3] = (mask & (1u << (i*4+3))) ? b.w : 0.f;
            p0 += m[i*4+0]; p1 += m[i*4+1]; p2 += m[i*4+2]; p3 += m[i*4+3];
        }
        #pragma unroll
        for (int k = 0; k < 32; k++) sel[k] *= PEN;     // overlaps DPP sum
        float part = wave_sum64((p0 + p1) + (p2 + p3));
        float inv = 1.f / part;

        // ---- sel update + candidate-masked value ----
        unsigned cm = mask & candBits;
        float cv[32];
        #pragma unroll
        for (int k = 0; k < 32; k++) {
            float s2 = fmaf(m[k], inv, sel[k]);
            sel[k] = s2;
            cv[k] = ((cm >> k) & 1u) ? s2 : INFINITY;
        }
        // ---- local min tree, then DPP min across lanes ----
        float m16[16];
        #pragma unroll
        for (int k = 0; k < 16; k++) m16[k] = fminf(cv[k], cv[k + 16]);
        float m8[8];
        #pragma unroll
        for (int k = 0; k < 8; k++) m8[k] = fminf(m16[k], m16[k + 8]);
        float m4[4];
        #pragma unroll
        for (int k = 0; k < 4; k++) m4[k] = fminf(m8[k], m8[k + 4]);
        float lmin = fminf(fminf(m4[0], m4[1]), fminf(m4[2], m4[3]));
        float gm = wave_min64f(lmin);

        // ---- first matching column: bitmask + ffs, then DPP min pos ----
        unsigned mb = 0;
        #pragma unroll
        for (int k = 0; k < 32; k++) mb |= (cv[k] == gm) ? (1u << k) : 0u;
        int mk = __ffs(mb) - 1;
        unsigned lpos = mb ? (unsigned)(((mk >> 2) << 8) + l * 4 + (mk & 3))
                           : 0xffffffffu;
        unsigned bpos = wave_min64u(lpos);

        // ---- evict ----
        int ke = (((bpos >> 8) << 2) | (bpos & 3));
        if ((((int)bpos >> 2) & 63) == l) mask &= ~(1u << ke);
        if (l == 0) et[bpos] = t;

        // ---- candidate set grows by one col for step t+1 ----
        int newc = t + 1 - RECENT;
        if (((newc >> 2) & 63) == l) candBits |= 1u << (((newc >> 8) << 2) | (newc & 3));

        // ---- rotate (forces lgkm wait for nxt), then release row t ----
        #pragma unroll
        for (int i = 0; i < 8; i++) cur[i] = nxt[i];
        if (l == 0) *(volatile int*)&consF = t;
    }

    #pragma unroll
    for (int s = 0; s < SEQ / 64; s++)
        evict[h * SEQ + s * 64 + l] = et[s * 64 + l];
}

// ---------------- apply mask + renormalize rows >= CACHEB in place --------
__global__ __launch_bounds__(256)
void mask_renorm(float* __restrict__ Sc, const int* __restrict__ evict)
{
    int r = CACHEB + blockIdx.x;
    int h = blockIdx.y;
    float* row = Sc + ((size_t)h * SEQ + r) * SEQ;
    const int* et = evict + h * SEQ;
    int tid = threadIdx.x;
    __shared__ float red[256];
    float v[8]; float sum = 0.f;
    #pragma unroll
    for (int s = 0; s < 8; s++) {
        int c = s * 256 + tid;
        float x = row[c];
        v[s] = (et[c] >= r) ? x : 0.f;
        sum += v[s];
    }
    red[tid] = sum; __syncthreads();
    for (int s = 128; s; s >>= 1) { if (tid < s) red[tid] += red[tid + s]; __syncthreads(); }
    float inv = 1.f / red[0];
    #pragma unroll
    for (int s = 0; s < 8; s++) row[s * 256 + tid] = v[s] * inv;
}

extern "C" void kernel_launch(void* const* d_in, const int* in_sizes, int n_in,
                              void* d_out, int out_size, void* d_ws, size_t ws_size,
                              hipStream_t stream)
{
    const float* hidden = (const float*)d_in[0];
    const int*   pos    = (const int*)d_in[2];
    const float* wq     = (const float*)d_in[3];
    const float* wk     = (const float*)d_in[4];
    const float* wv     = (const float*)d_in[5];
    const float* wo     = (const float*)d_in[6];
    float* out = (float*)d_out;

    float* ws = (float*)d_ws;
    const size_t SD = (size_t)SEQ * DIM;
    float* Q    = ws;            // 16 MB
    float* K    = ws + SD;       // 16 MB
    float* V    = ws + 2 * SD;   // 16 MB; reused as O after transpose_v
    float* Vt   = ws + 3 * SD;   // 16 MB
    float* O    = V;             // alias: V dead once Vt exists
    float* sel0 = ws + 4 * SD;                 // NH*SEQ floats
    int*   evct = (int*)(ws + 4 * SD + (size_t)NH * SEQ);  // NH*SEQ ints
    float* Sc   = ws + 4 * SD + 2 * (size_t)NH * SEQ;      // g * SEQ*SEQ floats

    const size_t fixedB   = (4 * SD + 2 * (size_t)NH * SEQ) * sizeof(float);
    const size_t perHeadB = (size_t)SEQ * SEQ * sizeof(float);
    int g = NH;
    while (g > 1 && fixedB + (size_t)g * perHeadB > ws_size) g >>= 1;

    // 1. projections: X @ W^T
    gemm_nt<<<dim3(32, 32, 1), 256, 0, stream>>>(hidden, wq, Q, SEQ, DIM, DIM,
        DIM, DIM, DIM, 0, 0, 0, 1.f, 0, 0);
    gemm_nt<<<dim3(32, 32, 1), 256, 0, stream>>>(hidden, wk, K, SEQ, DIM, DIM,
        DIM, DIM, DIM, 0, 0, 0, 1.f, 0, 0);
    gemm_nt<<<dim3(32, 32, 1), 256, 0, stream>>>(hidden, wv, V, SEQ, DIM, DIM,
        DIM, DIM, DIM, 0, 0, 0, 1.f, 0, 0);

    // 2. RoPE on Q, K
    rope_qk<<<dim3(SEQ, NH / 4), 256, 0, stream>>>(Q, K, pos);

    // 3. V -> Vt[h][hd][s]  (after this, V's storage becomes O)
    transpose_v<<<dim3(SEQ / 32, HD / 32, NH), dim3(32, 32), 0, stream>>>(V, Vt);

    // 4-8 per head-group (score buffer reused across groups)
    for (int h0 = 0; h0 < NH; h0 += g) {
        int gc = min(g, NH - h0);
        gemm_nt<<<dim3(32, 32, gc), 256, 0, stream>>>(
            Q + (size_t)h0 * HD, K + (size_t)h0 * HD, Sc, SEQ, SEQ, HD,
            DIM, DIM, SEQ, HD, HD, (long)SEQ * SEQ, QK_SCALE, 1, 0);
        softmax_rows<<<dim3(SEQ, gc), 256, 0, stream>>>(Sc);
        warmup_select<<<dim3(SEQ / 256, gc), 256, 0, stream>>>(Sc, sel0);
        h2o_scan4<<<dim3(gc), 128, 0, stream>>>(Sc, sel0, evct);
        mask_renorm<<<dim3(SEQ - CACHEB, gc), 256, 0, stream>>>(Sc, evct);
        gemm_nt<<<dim3(HD / 64, 32, gc), 256, 0, stream>>>(
            Sc, Vt + (size_t)h0 * HD * SEQ, O + (size_t)h0 * HD, SEQ, HD, SEQ,
            SEQ, SEQ, DIM, (long)SEQ * SEQ, (long)HD * SEQ, HD, 1.f, 0, 1);
    }

    // 9. final projection: out = O @ wo^T
    gemm_nt<<<dim3(32, 32, 1), 256, 0, stream>>>(O, wo, out, SEQ, DIM, DIM,
        DIM, DIM, DIM, 0, 0, 0, 1.f, 0, 0);
}

// Round 9
// 5170.805 us; speedup vs baseline: 1.2847x; 1.1349x over previous
//
#include <hip/hip_runtime.h>
#include <math.h>

#define SEQ 2048
#define DIM 2048
#define NH 16
#define HD 128
#define CACHEB 408
#define RECENT 204
#define PEN 0.4f
#define QK_SCALE 0.08838834764831845f  // 1/sqrt(128)
#define BIGT 0x7fffffff

typedef unsigned short u16;
typedef __attribute__((ext_vector_type(8))) short bh8;   // 8 bf16 (4 VGPRs)
typedef __attribute__((ext_vector_type(4))) float f32x4; // MFMA acc

__device__ __forceinline__ u16 f2bf(float x) {           // RNE f32->bf16
    unsigned u = __float_as_uint(x);
    return (u16)((u + 0x7fffu + ((u >> 16) & 1u)) >> 16);
}
__device__ __forceinline__ void splitf(float x, u16& h, u16& l) {
    h = f2bf(x);
    float hf = __uint_as_float(((unsigned)h) << 16);
    l = f2bf(x - hf);
}

// ---------------- f32 -> (hi,lo) bf16 split, 4 elems/thread ---------------
__global__ __launch_bounds__(256)
void split_kernel(const float* __restrict__ src, u16* __restrict__ dh,
                  u16* __restrict__ dl, int n4)
{
    int i = blockIdx.x * 256 + threadIdx.x;
    if (i >= n4) return;
    float4 v = ((const float4*)src)[i];
    union { u16 s[4]; unsigned long long q; } oh, ol;
    splitf(v.x, oh.s[0], ol.s[0]); splitf(v.y, oh.s[1], ol.s[1]);
    splitf(v.z, oh.s[2], ol.s[2]); splitf(v.w, oh.s[3], ol.s[3]);
    ((unsigned long long*)dh)[i] = oh.q;
    ((unsigned long long*)dl)[i] = ol.q;
}

// ---------------- split-bf16 MFMA NT GEMM ---------------------------------
// C = scale * A(MxK) * B(NxK)^T with A ~ Ah+Al, B ~ Bh+Bl (bf16 pairs):
//   acc += Ah*Bh + Ah*Bl + Al*Bh      (~f32 accuracy, 3x MFMA)
// ASPLITF32/BSPLITF32: operand given as f32, split in-register.
// 128x128 tile, 4 waves, fragments direct from global.
// Fragment layouts (verified on-device, rounds 7-8):
//   A/B: lane=16*quad+r holds [r][quad*8 + 0..7]; C/D: col=lane&15, row=quad*4+reg
template<bool ASPLITF32, bool BSPLITF32, bool CAUSAL, bool TRUNCA>
__global__ __launch_bounds__(256, 2)
void mfma_nt(const void* __restrict__ Ah_, const void* __restrict__ Al_,
             const void* __restrict__ Bh_, const void* __restrict__ Bl_,
             float* __restrict__ Cp, int K, int lda, int ldb, int ldc,
             long aB, long bB, long cB, float scale)
{
    int m0 = blockIdx.y * 128, n0 = blockIdx.x * 128;
    if (CAUSAL && n0 > m0 + 127) return;

    const float* Af = (const float*)Ah_ + (size_t)blockIdx.z * aB;
    const u16*   Ah = (const u16*)Ah_   + (size_t)blockIdx.z * aB;
    const u16*   Al = (const u16*)Al_   + (size_t)blockIdx.z * aB;
    const float* Bf = (const float*)Bh_ + (size_t)blockIdx.z * bB;
    const u16*   Bh = (const u16*)Bh_   + (size_t)blockIdx.z * bB;
    const u16*   Bl = (const u16*)Bl_   + (size_t)blockIdx.z * bB;
    float* C = Cp + (size_t)blockIdx.z * cB;

    int lane = threadIdx.x & 63, wave = threadIdx.x >> 6;
    int wm = m0 + (wave >> 1) * 64, wn = n0 + (wave & 1) * 64;
    int fr = lane & 15, quad = lane >> 4;
    int kq = quad * 8;

    auto loadA = [&](int mt, int k, bh8& h, bh8& l) {
        int r = wm + mt * 16 + fr;
        if (ASPLITF32) {
            const float* p = Af + (size_t)r * lda + k + kq;
            float4 x = *(const float4*)p, y = *(const float4*)(p + 4);
            u16 hh, ll;
            splitf(x.x,hh,ll); h[0]=(short)hh; l[0]=(short)ll;
            splitf(x.y,hh,ll); h[1]=(short)hh; l[1]=(short)ll;
            splitf(x.z,hh,ll); h[2]=(short)hh; l[2]=(short)ll;
            splitf(x.w,hh,ll); h[3]=(short)hh; l[3]=(short)ll;
            splitf(y.x,hh,ll); h[4]=(short)hh; l[4]=(short)ll;
            splitf(y.y,hh,ll); h[5]=(short)hh; l[5]=(short)ll;
            splitf(y.z,hh,ll); h[6]=(short)hh; l[6]=(short)ll;
            splitf(y.w,hh,ll); h[7]=(short)hh; l[7]=(short)ll;
        } else {
            h = *(const bh8*)(Ah + (size_t)r * lda + k + kq);
            l = *(const bh8*)(Al + (size_t)r * lda + k + kq);
        }
    };
    auto loadB = [&](int nt, int k, bh8& h, bh8& l) {
        int r = wn + nt * 16 + fr;
        if (BSPLITF32) {
            const float* p = Bf + (size_t)r * ldb + k + kq;
            float4 x = *(const float4*)p, y = *(const float4*)(p + 4);
            u16 hh, ll;
            splitf(x.x,hh,ll); h[0]=(short)hh; l[0]=(short)ll;
            splitf(x.y,hh,ll); h[1]=(short)hh; l[1]=(short)ll;
            splitf(x.z,hh,ll); h[2]=(short)hh; l[2]=(short)ll;
            splitf(x.w,hh,ll); h[3]=(short)hh; l[3]=(short)ll;
            splitf(y.x,hh,ll); h[4]=(short)hh; l[4]=(short)ll;
            splitf(y.y,hh,ll); h[5]=(short)hh; l[5]=(short)ll;
            splitf(y.z,hh,ll); h[6]=(short)hh; l[6]=(short)ll;
            splitf(y.w,hh,ll); h[7]=(short)hh; l[7]=(short)ll;
        } else {
            h = *(const bh8*)(Bh + (size_t)r * ldb + k + kq);
            l = *(const bh8*)(Bl + (size_t)r * ldb + k + kq);
        }
    };

    f32x4 acc[4][4] = {};
    int Keff = TRUNCA ? min(K, m0 + 128) : K;

    for (int k0 = 0; k0 < Keff; k0 += 32) {
        bh8 ah[4], al[4], bh[4], bl[4];
        #pragma unroll
        for (int i = 0; i < 4; i++) { loadA(i, k0, ah[i], al[i]); loadB(i, k0, bh[i], bl[i]); }
        #pragma unroll
        for (int mt = 0; mt < 4; mt++)
            #pragma unroll
            for (int nt = 0; nt < 4; nt++) {
                acc[mt][nt] = __builtin_amdgcn_mfma_f32_16x16x32_bf16(ah[mt], bh[nt], acc[mt][nt], 0, 0, 0);
                acc[mt][nt] = __builtin_amdgcn_mfma_f32_16x16x32_bf16(ah[mt], bl[nt], acc[mt][nt], 0, 0, 0);
                acc[mt][nt] = __builtin_amdgcn_mfma_f32_16x16x32_bf16(al[mt], bh[nt], acc[mt][nt], 0, 0, 0);
            }
    }

    #pragma unroll
    for (int mt = 0; mt < 4; mt++)
        #pragma unroll
        for (int r = 0; r < 4; r++) {
            int row = wm + mt * 16 + quad * 4 + r;
            #pragma unroll
            for (int nt = 0; nt < 4; nt++) {
                int col = wn + nt * 16 + fr;
                C[(size_t)row * ldc + col] = acc[mt][nt][r] * scale;
            }
        }
}

// ---------------- RoPE in place on Q and K (f32) ---------------------------
__global__ __launch_bounds__(256)
void rope_qk(float* __restrict__ Q, float* __restrict__ K, const int* __restrict__ pos_ids)
{
    int s = blockIdx.x;
    int i = threadIdx.x & 63;
    int h = blockIdx.y * 4 + (threadIdx.x >> 6);
    double p = (double)pos_ids[s];
    double invf = exp(-((double)(2 * i) / (double)HD) * 9.210340371976184); // ln(10000)
    double ang = p * invf;
    float c = (float)cos(ang), sn = (float)sin(ang);
    size_t b = (size_t)s * DIM + (size_t)h * HD;
    float q0 = Q[b + i], q1 = Q[b + i + 64];
    Q[b + i]      = q0 * c - q1 * sn;
    Q[b + i + 64] = q1 * c + q0 * sn;
    float k0 = K[b + i], k1 = K[b + i + 64];
    K[b + i]      = k0 * c - k1 * sn;
    K[b + i + 64] = k1 * c + k0 * sn;
}

// ---------------- V(f32) -> Vt hi/lo bf16 [h][hd][s] -----------------------
__global__ __launch_bounds__(1024)
void transpose_v(const float* __restrict__ V, u16* __restrict__ Vth, u16* __restrict__ Vtl)
{
    __shared__ float tile[32][33];
    int h = blockIdx.z;
    int j0 = blockIdx.x * 32, d0 = blockIdx.y * 32;
    int tx = threadIdx.x, ty = threadIdx.y;
    tile[ty][tx] = V[(size_t)(j0 + ty) * DIM + (size_t)h * HD + d0 + tx];
    __syncthreads();
    u16 hh, ll; splitf(tile[tx][ty], hh, ll);
    size_t idx = (size_t)h * HD * SEQ + (size_t)(d0 + ty) * SEQ + j0 + tx;
    Vth[idx] = hh; Vtl[idx] = ll;
}

// ---------------- row softmax (causal) in place on Sc ---------------------
__global__ __launch_bounds__(256)
void softmax_rows(float* __restrict__ Sc)
{
    int r = blockIdx.x, h = blockIdx.y;
    float* row = Sc + ((size_t)h * SEQ + r) * SEQ;
    int n = r + 1;
    __shared__ float red[256];
    int tid = threadIdx.x;
    float mx = -INFINITY;
    for (int j = tid; j < n; j += 256) mx = fmaxf(mx, row[j]);
    red[tid] = mx; __syncthreads();
    for (int s = 128; s; s >>= 1) { if (tid < s) red[tid] = fmaxf(red[tid], red[tid + s]); __syncthreads(); }
    mx = red[0]; __syncthreads();
    float sum = 0.f;
    for (int j = tid; j < n; j += 256) { float e = expf(row[j] - mx); row[j] = e; sum += e; }
    red[tid] = sum; __syncthreads();
    for (int s = 128; s; s >>= 1) { if (tid < s) red[tid] += red[tid + s]; __syncthreads(); }
    float inv = 1.f / red[0];
    for (int j = tid; j < n; j += 256) row[j] *= inv;
    for (int j = n + tid; j < SEQ; j += 256) row[j] = 0.f;
}

// ---------------- parallel warmup: select0[h][c] = sum_t PEN^(407-t)*Sc[t][c]
__global__ __launch_bounds__(256)
void warmup_select(const float* __restrict__ Sc, float* __restrict__ sel0)
{
    int h = blockIdx.y;
    int col = blockIdx.x * 256 + threadIdx.x;
    const float* S = Sc + (size_t)h * SEQ * SEQ + col;
    float s = 0.f;
    #pragma unroll 4
    for (int t = 0; t < CACHEB; t++) s = PEN * s + S[(size_t)t * SEQ];
    sel0[h * SEQ + col] = s;
}

// ---------------- DPP cross-lane helpers ----------------------------------
#define DPP_SUMSTEP(x, ctrl) \
    x += __int_as_float(__builtin_amdgcn_update_dpp(0, __float_as_int(x), ctrl, 0xF, 0xF, true))
#define DPP_SUMBC(x, ctrl) \
    x += __int_as_float(__builtin_amdgcn_update_dpp(0, __float_as_int(x), ctrl, 0xF, 0xF, false))
#define DPP_MINF(x, ctrl) \
    x = fminf(x, __int_as_float(__builtin_amdgcn_update_dpp(__float_as_int(x), __float_as_int(x), ctrl, 0xF, 0xF, false)))
#define DPP_MINU(x, ctrl) \
    { unsigned t_ = (unsigned)__builtin_amdgcn_update_dpp((int)(x), (int)(x), ctrl, 0xF, 0xF, false); x = t_ < x ? t_ : x; }

__device__ __forceinline__ float wave_sum64(float x) {
    DPP_SUMSTEP(x, 0x111); DPP_SUMSTEP(x, 0x112);
    DPP_SUMSTEP(x, 0x114); DPP_SUMSTEP(x, 0x118);
    DPP_SUMBC(x, 0x142);   DPP_SUMBC(x, 0x143);
    return __int_as_float(__builtin_amdgcn_readlane(__float_as_int(x), 63));
}
__device__ __forceinline__ float wave_min64f(float x) {
    DPP_MINF(x, 0x111); DPP_MINF(x, 0x112);
    DPP_MINF(x, 0x114); DPP_MINF(x, 0x118);
    DPP_MINF(x, 0x142); DPP_MINF(x, 0x143);
    return __int_as_float(__builtin_amdgcn_readlane(__float_as_int(x), 63));
}
__device__ __forceinline__ unsigned wave_min64u(unsigned x) {
    DPP_MINU(x, 0x111); DPP_MINU(x, 0x112);
    DPP_MINU(x, 0x114); DPP_MINU(x, 0x118);
    DPP_MINU(x, 0x142); DPP_MINU(x, 0x143);
    return (unsigned)__builtin_amdgcn_readlane((int)x, 63);
}

#define SLOTS 8

// ---------------- H2O scan (producer/consumer wave specialization) --------
__global__ __launch_bounds__(128, 1)
void h2o_scan4(const float* __restrict__ Sc, const float* __restrict__ sel0,
               int* __restrict__ evict)
{
    __shared__ float ring[SLOTS * SEQ];   // 64 KB
    __shared__ int et[SEQ];               // 8 KB
    __shared__ int prodF, consF;

    int h = blockIdx.x;
    int tid = threadIdx.x;
    int l = tid & 63;
    int wv = tid >> 6;
    const float* Sh = Sc + (size_t)h * SEQ * SEQ;
    const float* gb = Sh + (l << 2);

    if (tid == 0) { prodF = CACHEB; consF = CACHEB - 1; }
    __syncthreads();

    if (wv == 1) {
        float4 ba[8], bb[8], bc[8];
        auto loadrow = [&](int r, float4 (&b)[8]) {
            const float* g = gb + (size_t)r * SEQ;
            #pragma unroll
            for (int i = 0; i < 8; i++) b[i] = *(const float4*)(g + i * 256);
        };
        auto writerow = [&](int r, float4 (&b)[8]) {
            while (*(volatile int*)&consF < r - SLOTS) __builtin_amdgcn_s_sleep(2);
            float* lp = &ring[(r % SLOTS) * SEQ] + (l << 2);
            #pragma unroll
            for (int i = 0; i < 8; i++) *(float4*)(lp + i * 256) = b[i];
            __threadfence_block();
            if (l == 0) *(volatile int*)&prodF = r + 1;
        };
        loadrow(CACHEB, ba); loadrow(CACHEB + 1, bb); loadrow(CACHEB + 2, bc);
        for (int r = CACHEB; r < SEQ; r += 3) {
            writerow(r, ba); if (r + 3 < SEQ) loadrow(r + 3, ba);
            if (r + 1 < SEQ) { writerow(r + 1, bb); if (r + 4 < SEQ) loadrow(r + 4, bb); }
            if (r + 2 < SEQ) { writerow(r + 2, bc); if (r + 5 < SEQ) loadrow(r + 5, bc); }
        }
        return;
    }

    #pragma unroll
    for (int s = 0; s < SEQ / 64; s++) et[s * 64 + l] = BIGT;

    float sel[32];
    const float* s0 = sel0 + h * SEQ + l * 4;
    #pragma unroll
    for (int i = 0; i < 8; i++) {
        float4 v = *(const float4*)(s0 + i * 256);
        sel[i*4+0]=v.x; sel[i*4+1]=v.y; sel[i*4+2]=v.z; sel[i*4+3]=v.w;
    }

    while (*(volatile int*)&prodF < CACHEB + 1) __builtin_amdgcn_s_sleep(1);
    float4 cur[8], nxt[8];
    {
        const float* lp = &ring[(CACHEB % SLOTS) * SEQ] + (l << 2);
        #pragma unroll
        for (int i = 0; i < 8; i++) cur[i] = *(const float4*)(lp + i * 256);
    }

    unsigned mask = 0xffffffffu;
    unsigned candBits = 0;
    #pragma unroll
    for (int k = 0; k < 32; k++) {
        int p = ((k >> 2) << 8) + l * 4 + (k & 3);
        if (p <= CACHEB - RECENT) candBits |= 1u << k;
    }

    for (int t = CACHEB; t < SEQ - 1; t++) {
        while (*(volatile int*)&prodF < t + 2) __builtin_amdgcn_s_sleep(1);
        {
            const float* lp = &ring[((t + 1) % SLOTS) * SEQ] + (l << 2);
            #pragma unroll
            for (int i = 0; i < 8; i++) nxt[i] = *(const float4*)(lp + i * 256);
        }

        float m[32];
        float p0 = 0.f, p1 = 0.f, p2 = 0.f, p3 = 0.f;
        #pragma unroll
        for (int i = 0; i < 8; i++) {
            float4 b = cur[i];
            m[i*4+0] = (mask & (1u << (i*4+0))) ? b.x : 0.f;
            m[i*4+1] = (mask & (1u << (i*4+1))) ? b.y : 0.f;
            m[i*4+2] = (mask & (1u << (i*4+2))) ? b.z : 0.f;
            m[i*4+3] = (mask & (1u << (i*4+3))) ? b.w : 0.f;
            p0 += m[i*4+0]; p1 += m[i*4+1]; p2 += m[i*4+2]; p3 += m[i*4+3];
        }
        #pragma unroll
        for (int k = 0; k < 32; k++) sel[k] *= PEN;
        float part = wave_sum64((p0 + p1) + (p2 + p3));
        float inv = 1.f / part;

        unsigned cm = mask & candBits;
        float cv[32];
        #pragma unroll
        for (int k = 0; k < 32; k++) {
            float s2 = fmaf(m[k], inv, sel[k]);
            sel[k] = s2;
            cv[k] = ((cm >> k) & 1u) ? s2 : INFINITY;
        }
        float m16[16];
        #pragma unroll
        for (int k = 0; k < 16; k++) m16[k] = fminf(cv[k], cv[k + 16]);
        float m8[8];
        #pragma unroll
        for (int k = 0; k < 8; k++) m8[k] = fminf(m16[k], m16[k + 8]);
        float m4[4];
        #pragma unroll
        for (int k = 0; k < 4; k++) m4[k] = fminf(m8[k], m8[k + 4]);
        float lmin = fminf(fminf(m4[0], m4[1]), fminf(m4[2], m4[3]));
        float gm = wave_min64f(lmin);

        unsigned mb = 0;
        #pragma unroll
        for (int k = 0; k < 32; k++) mb |= (cv[k] == gm) ? (1u << k) : 0u;
        int mk = __ffs(mb) - 1;
        unsigned lpos = mb ? (unsigned)(((mk >> 2) << 8) + l * 4 + (mk & 3))
                           : 0xffffffffu;
        unsigned bpos = wave_min64u(lpos);

        int ke = (((bpos >> 8) << 2) | (bpos & 3));
        if ((((int)bpos >> 2) & 63) == l) mask &= ~(1u << ke);
        if (l == 0) et[bpos] = t;

        int newc = t + 1 - RECENT;
        if (((newc >> 2) & 63) == l) candBits |= 1u << (((newc >> 8) << 2) | (newc & 3));

        #pragma unroll
        for (int i = 0; i < 8; i++) cur[i] = nxt[i];
        if (l == 0) *(volatile int*)&consF = t;
    }

    #pragma unroll
    for (int s = 0; s < SEQ / 64; s++)
        evict[h * SEQ + s * 64 + l] = et[s * 64 + l];
}

// ---------------- apply mask + renormalize rows >= CACHEB in place --------
__global__ __launch_bounds__(256)
void mask_renorm(float* __restrict__ Sc, const int* __restrict__ evict)
{
    int r = CACHEB + blockIdx.x;
    int h = blockIdx.y;
    float* row = Sc + ((size_t)h * SEQ + r) * SEQ;
    const int* et = evict + h * SEQ;
    int tid = threadIdx.x;
    __shared__ float red[256];
    float v[8]; float sum = 0.f;
    #pragma unroll
    for (int s = 0; s < 8; s++) {
        int c = s * 256 + tid;
        float x = row[c];
        v[s] = (et[c] >= r) ? x : 0.f;
        sum += v[s];
    }
    red[tid] = sum; __syncthreads();
    for (int s = 128; s; s >>= 1) { if (tid < s) red[tid] += red[tid + s]; __syncthreads(); }
    float inv = 1.f / red[0];
    #pragma unroll
    for (int s = 0; s < 8; s++) row[s * 256 + tid] = v[s] * inv;
}

extern "C" void kernel_launch(void* const* d_in, const int* in_sizes, int n_in,
                              void* d_out, int out_size, void* d_ws, size_t ws_size,
                              hipStream_t stream)
{
    const float* hidden = (const float*)d_in[0];
    const int*   pos    = (const int*)d_in[2];
    const float* wq     = (const float*)d_in[3];
    const float* wk     = (const float*)d_in[4];
    const float* wv     = (const float*)d_in[5];
    const float* wo     = (const float*)d_in[6];
    float* out = (float*)d_out;

    float* ws = (float*)d_ws;
    const size_t SD = (size_t)SEQ * DIM;           // 4M elems
    float* Q    = ws;                              // f32, 16 MB
    float* K    = ws + SD;                         // f32, 16 MB
    float* V    = ws + 2 * SD;                     // f32; becomes O after transpose
    float* O    = V;
    u16*   Vth  = (u16*)(ws + 3 * SD);             // bf16-hi Vt (8 MB)
    u16*   Vtl  = Vth + SD;                        // bf16-lo Vt (8 MB)
    float* sel0 = ws + 4 * SD;                     // NH*SEQ floats
    int*   evct = (int*)(ws + 4 * SD + (size_t)NH * SEQ);
    float* Sc   = ws + 4 * SD + 2 * (size_t)NH * SEQ;   // g * SEQ*SEQ floats

    // staging (hi/lo splits) in the not-yet-used Sc region: 4 arrays x SD u16
    u16* hh = (u16*)Sc;        // hidden hi
    u16* hl = hh + SD;         // hidden lo
    u16* wh = hl + SD;         // current weight hi (reused per weight)
    u16* wl = wh + SD;         // current weight lo

    const size_t fixedB   = (4 * SD + 2 * (size_t)NH * SEQ) * sizeof(float);
    const size_t perHeadB = (size_t)SEQ * SEQ * sizeof(float);
    int g = NH;
    while (g > 1 && fixedB + (size_t)g * perHeadB > ws_size) g >>= 1;

    const int N4 = (int)(SD / 4);
    const int CB = (N4 + 255) / 256;

    // 0-1. split + projections (weights staged sequentially)
    split_kernel<<<CB, 256, 0, stream>>>(hidden, hh, hl, N4);
    split_kernel<<<CB, 256, 0, stream>>>(wq, wh, wl, N4);
    mfma_nt<false,false,false,false><<<dim3(16,16,1), 256, 0, stream>>>(
        hh, hl, wh, wl, Q, DIM, DIM, DIM, DIM, 0, 0, 0, 1.f);
    split_kernel<<<CB, 256, 0, stream>>>(wk, wh, wl, N4);
    mfma_nt<false,false,false,false><<<dim3(16,16,1), 256, 0, stream>>>(
        hh, hl, wh, wl, K, DIM, DIM, DIM, DIM, 0, 0, 0, 1.f);
    split_kernel<<<CB, 256, 0, stream>>>(wv, wh, wl, N4);
    mfma_nt<false,false,false,false><<<dim3(16,16,1), 256, 0, stream>>>(
        hh, hl, wh, wl, V, DIM, DIM, DIM, DIM, 0, 0, 0, 1.f);

    // 2. RoPE on Q, K (f32, in place)
    rope_qk<<<dim3(SEQ, NH / 4), 256, 0, stream>>>(Q, K, pos);

    // 3. V -> Vt hi/lo (V storage then becomes O)
    transpose_v<<<dim3(SEQ / 32, HD / 32, NH), dim3(32, 32), 0, stream>>>(V, Vth, Vtl);

    // 4-8 per head-group
    for (int h0 = 0; h0 < NH; h0 += g) {
        int gc = min(g, NH - h0);
        // QK logits: f32 Q,K split in-register, causal tiles, f32 out
        mfma_nt<true,true,true,false><<<dim3(16,16,gc), 256, 0, stream>>>(
            Q + (size_t)h0 * HD, nullptr, K + (size_t)h0 * HD, nullptr, Sc, HD,
            DIM, DIM, SEQ, HD, HD, (long)SEQ * SEQ, QK_SCALE);
        softmax_rows<<<dim3(SEQ, gc), 256, 0, stream>>>(Sc);
        warmup_select<<<dim3(SEQ / 256, gc), 256, 0, stream>>>(Sc, sel0);
        h2o_scan4<<<dim3(gc), 128, 0, stream>>>(Sc, sel0, evct);
        mask_renorm<<<dim3(SEQ - CACHEB, gc), 256, 0, stream>>>(Sc, evct);
        // PV: probs f32 split in-register (K-truncated), Vt pre-split, f32 out
        mfma_nt<true,false,false,true><<<dim3(1,16,gc), 256, 0, stream>>>(
            Sc, nullptr, Vth + (size_t)h0 * HD * SEQ, Vtl + (size_t)h0 * HD * SEQ,
            O + (size_t)h0 * HD, SEQ, SEQ, SEQ, DIM,
            (long)SEQ * SEQ, (long)HD * SEQ, HD, 1.f);
    }

    // 9. final projection: out = O @ wo^T (O split in-register, wo pre-split)
    split_kernel<<<CB, 256, 0, stream>>>(wo, wh, wl, N4);
    mfma_nt<true,false,false,false><<<dim3(16,16,1), 256, 0, stream>>>(
        O, nullptr, wh, wl, out, DIM, DIM, DIM, DIM, 0, 0, 0, 1.f);
}